// Round 5
// baseline (439.335 us; speedup 1.0000x reference)
//
#include <hip/hip_runtime.h>
#include <math.h>

#define HD 4096  // H == D == 4096

typedef float v4f __attribute__((ext_vector_type(4)));  // clang-native for nt builtins

// ---------------------------------------------------------------------------
// Kernel 1 (split): GEMV for ONE matrix. Grid 1024 blocks x 256 threads,
// one wave per row, 4 rows/block. Launched 6x (once per weight matrix) so the
// profiler reports each piece AND forces k_ct into the top-5 with counters.
// Inner code identical to the fused round-4 version.
// ---------------------------------------------------------------------------
__global__ __launch_bounds__(256, 6) void k_gemv1(
    const float* __restrict__ x,
    const float* __restrict__ W,
    float* __restrict__ dots_out)   // = ws_dots + mat*HD
{
    __shared__ float xs[HD];
    const int tid = threadIdx.x;
    {
        const float4* x4  = (const float4*)x;
        float4*       sx4 = (float4*)xs;
#pragma unroll
        for (int i = 0; i < 4; ++i) sx4[i * 256 + tid] = x4[i * 256 + tid];
    }
    __syncthreads();

    const int wave = tid >> 6;
    const int lane = tid & 63;
    const int row  = (blockIdx.x << 2) | wave;   // 0..4095

    const float4* Wrow = (const float4*)(W + (size_t)row * HD) + lane;
    const float4* sx4  = (const float4*)xs + lane;

    float a0 = 0.f, a1 = 0.f;
#pragma unroll
    for (int t = 0; t < 16; t += 2) {
        float4 w0 = Wrow[t * 64];
        float4 x0 = sx4[t * 64];
        float4 w1 = Wrow[(t + 1) * 64];
        float4 x1 = sx4[(t + 1) * 64];
        a0 += w0.x * x0.x + w0.y * x0.y + w0.z * x0.z + w0.w * x0.w;
        a1 += w1.x * x1.x + w1.y * x1.y + w1.z * x1.z + w1.w * x1.w;
    }
    float acc = a0 + a1;
#pragma unroll
    for (int off = 32; off > 0; off >>= 1)
        acc += __shfl_xor(acc, off, 64);

    if (lane == 0) dots_out[row] = acc;
}

// ---------------------------------------------------------------------------
// Kernel 2: gate math for all 4096 rows + per-block partials of n_t . q.
// 16 blocks x 256 threads, one row per thread, fully coalesced.
// ---------------------------------------------------------------------------
__global__ __launch_bounds__(256) void k_gates(
    const float* __restrict__ ws_dots,
    const float* __restrict__ bq, const float* __restrict__ bk,
    const float* __restrict__ bv, const float* __restrict__ bi,
    const float* __restrict__ bf, const float* __restrict__ bo,
    const float* __restrict__ n_prev, const float* __restrict__ m_prev,
    float* __restrict__ ws_q, float* __restrict__ ws_v,
    float* __restrict__ ws_o, float* __restrict__ ws_fg,
    float* __restrict__ ws_ik,
    float* __restrict__ out_n, float* __restrict__ out_m,
    float* __restrict__ ws_nq)
{
    const int tid = threadIdx.x;
    const int row = blockIdx.x * 256 + tid;

    float dq  = ws_dots[0 * HD + row];
    float dk  = ws_dots[1 * HD + row];
    float dv  = ws_dots[2 * HD + row];
    float di  = ws_dots[3 * HD + row];
    float df  = ws_dots[4 * HD + row];
    float d_o = ws_dots[5 * HD + row];

    float q  = dq + bq[row];
    float k  = (dk + bk[row]) * (1.0f / 64.0f);   // 1/sqrt(4096)
    float v  = dv + bv[row];
    float o  = 1.0f / (1.0f + expf(-(d_o + bo[row])));
    float it = di + bi[row];
    float ft = df + bf[row];
    float mp = m_prev[row];
    float mt = fmaxf(ft + mp, it);
    float ig = expf(it - mt);
    float fg = expf(ft + mp - mt);
    float nt = fg * n_prev[row] + ig * k;

    ws_q[row]  = q;
    ws_v[row]  = v;
    ws_o[row]  = o;
    ws_fg[row] = fg;
    ws_ik[row] = ig * k;
    out_n[row] = nt;
    out_m[row] = mt;

    float acc = nt * q;
#pragma unroll
    for (int off = 32; off > 0; off >>= 1)
        acc += __shfl_xor(acc, off, 64);
    __shared__ float red[4];
    if ((tid & 63) == 0) red[tid >> 6] = acc;
    __syncthreads();
    if (tid == 0) ws_nq[blockIdx.x] = red[0] + red[1] + red[2] + red[3];
}

// ---------------------------------------------------------------------------
// Kernel 3: c_t = f_g[c]*c_prev[r][c] + ik[c]*v[r], fused with
// h_t[r] = o[r] * (c_t[r,:] . q) / denom.  2 rows per block, 2048 blocks.
// UNCHANGED from round 4 — this round exposes its counters; round 6 fixes it.
// ---------------------------------------------------------------------------
__global__ __launch_bounds__(256) void k_ct(
    const float* __restrict__ c_prev,
    const float* __restrict__ ws_q, const float* __restrict__ ws_v,
    const float* __restrict__ ws_o, const float* __restrict__ ws_fg,
    const float* __restrict__ ws_ik, const float* __restrict__ ws_nq,
    float* __restrict__ out_h, float* __restrict__ out_c)
{
    const int row0 = blockIdx.x << 1;
    const int tid  = threadIdx.x;

    float den = 0.f;
#pragma unroll
    for (int i = 0; i < 16; ++i) den += ws_nq[i];
    den = fmaxf(fabsf(den), 1.0f);

    const float v0 = ws_v[row0];
    const float v1 = ws_v[row0 + 1];

    const v4f* cp0 = (const v4f*)(c_prev + (size_t)row0 * HD);
    const v4f* cp1 = cp0 + HD / 4;
    v4f*       ct0 = (v4f*)(out_c + (size_t)row0 * HD);
    v4f*       ct1 = ct0 + HD / 4;
    const v4f* fg4 = (const v4f*)ws_fg;
    const v4f* ik4 = (const v4f*)ws_ik;
    const v4f* q4  = (const v4f*)ws_q;

    v4f c0[4], c1[4], f[4], k[4], qv[4];
#pragma unroll
    for (int t = 0; t < 4; ++t) {
        const int idx = t * 256 + tid;
        c0[t] = __builtin_nontemporal_load(&cp0[idx]);
        c1[t] = __builtin_nontemporal_load(&cp1[idx]);
        f[t]  = fg4[idx];
        k[t]  = ik4[idx];
        qv[t] = q4[idx];
    }

    float acc0 = 0.f, acc1 = 0.f;
#pragma unroll
    for (int t = 0; t < 4; ++t) {
        const int idx = t * 256 + tid;
        v4f a = f[t] * c0[t] + k[t] * v0;
        v4f b = f[t] * c1[t] + k[t] * v1;
        __builtin_nontemporal_store(a, &ct0[idx]);
        __builtin_nontemporal_store(b, &ct1[idx]);
        acc0 += a.x * qv[t].x + a.y * qv[t].y + a.z * qv[t].z + a.w * qv[t].w;
        acc1 += b.x * qv[t].x + b.y * qv[t].y + b.z * qv[t].z + b.w * qv[t].w;
    }
#pragma unroll
    for (int off = 32; off > 0; off >>= 1) {
        acc0 += __shfl_xor(acc0, off, 64);
        acc1 += __shfl_xor(acc1, off, 64);
    }
    __shared__ float red[2][4];
    if ((tid & 63) == 0) {
        red[0][tid >> 6] = acc0;
        red[1][tid >> 6] = acc1;
    }
    __syncthreads();
    if (tid == 0) {
        float s0 = red[0][0] + red[0][1] + red[0][2] + red[0][3];
        float s1 = red[1][0] + red[1][1] + red[1][2] + red[1][3];
        out_h[row0]     = ws_o[row0]     * s0 / den;
        out_h[row0 + 1] = ws_o[row0 + 1] * s1 / den;
    }
}

// ---------------------------------------------------------------------------
extern "C" void kernel_launch(void* const* d_in, const int* in_sizes, int n_in,
                              void* d_out, int out_size, void* d_ws, size_t ws_size,
                              hipStream_t stream) {
    const float* x      = (const float*)d_in[0];
    /* d_in[1] = h_prev: unused by the reference */
    const float* c_prev = (const float*)d_in[2];
    const float* n_prev = (const float*)d_in[3];
    const float* m_prev = (const float*)d_in[4];
    const float* Wq = (const float*)d_in[5];  const float* bq = (const float*)d_in[6];
    const float* Wk = (const float*)d_in[7];  const float* bk = (const float*)d_in[8];
    const float* Wv = (const float*)d_in[9];  const float* bv = (const float*)d_in[10];
    const float* Wi = (const float*)d_in[11]; const float* bi = (const float*)d_in[12];
    const float* Wf = (const float*)d_in[13]; const float* bf = (const float*)d_in[14];
    const float* Wo = (const float*)d_in[15]; const float* bo = (const float*)d_in[16];

    // Output layout: h_t [H], c_t [H,H], n_t [H], m_t [H] — flat concat.
    float* out   = (float*)d_out;
    float* out_h = out;
    float* out_c = out + HD;
    float* out_n = out + HD + (size_t)HD * HD;
    float* out_m = out_n + HD;

    // Workspace layout (floats): dots[6*HD], q, v, o, f_g, i_g*k, nq[16]
    float* ws      = (float*)d_ws;
    float* ws_dots = ws;
    float* ws_q    = ws + 6 * HD;
    float* ws_v    = ws + 7 * HD;
    float* ws_o    = ws + 8 * HD;
    float* ws_fg   = ws + 9 * HD;
    float* ws_ik   = ws + 10 * HD;
    float* ws_nq   = ws + 11 * HD;   // 16 floats

    k_gemv1<<<1024, 256, 0, stream>>>(x, Wq, ws_dots + 0 * HD);
    k_gemv1<<<1024, 256, 0, stream>>>(x, Wk, ws_dots + 1 * HD);
    k_gemv1<<<1024, 256, 0, stream>>>(x, Wv, ws_dots + 2 * HD);
    k_gemv1<<<1024, 256, 0, stream>>>(x, Wi, ws_dots + 3 * HD);
    k_gemv1<<<1024, 256, 0, stream>>>(x, Wf, ws_dots + 4 * HD);
    k_gemv1<<<1024, 256, 0, stream>>>(x, Wo, ws_dots + 5 * HD);
    k_gates<<<16, 256, 0, stream>>>(ws_dots, bq, bk, bv, bi, bf, bo,
                                    n_prev, m_prev,
                                    ws_q, ws_v, ws_o, ws_fg, ws_ik,
                                    out_n, out_m, ws_nq);
    k_ct<<<2048, 256, 0, stream>>>(c_prev, ws_q, ws_v, ws_o, ws_fg, ws_ik,
                                   ws_nq, out_h, out_c);
}

// Round 6
// 432.719 us; speedup vs baseline: 1.0153x; 1.0153x over previous
//
#include <hip/hip_runtime.h>
#include <math.h>

#define HD 4096  // H == D == 4096

typedef float v4f __attribute__((ext_vector_type(4)));  // clang-native for nt builtins

// ---------------------------------------------------------------------------
// Kernel 1: 6-way GEMV, one wave per (matrix, row).  AT THE READ ROOFLINE:
// 402 MB of single-touch weights / ~3.2 TB/s pure-read ceiling = ~125 us.
// (Verified: 3 structurally different variants + m13 copy read-side all pin
// at ~3.2 TB/s; the harness restore-fill shows the write path alone does 6.9.)
// ---------------------------------------------------------------------------
__global__ __launch_bounds__(256, 6) void k_gemv(
    const float* __restrict__ x,
    const float* __restrict__ Wq, const float* __restrict__ Wk,
    const float* __restrict__ Wv, const float* __restrict__ Wi,
    const float* __restrict__ Wf, const float* __restrict__ Wo,
    float* __restrict__ ws_dots)
{
    __shared__ float xs[HD];
    const int tid = threadIdx.x;
    {
        const float4* x4  = (const float4*)x;
        float4*       sx4 = (float4*)xs;
#pragma unroll
        for (int i = 0; i < 4; ++i) sx4[i * 256 + tid] = x4[i * 256 + tid];
    }
    __syncthreads();

    const int wave = tid >> 6;
    const int lane = tid & 63;
    const int mat  = blockIdx.x >> 10;                       // 0..5, block-uniform
    const int row  = ((blockIdx.x & 1023) << 2) | wave;      // 0..4095

    const float* W = Wq;
    if      (mat == 1) W = Wk;
    else if (mat == 2) W = Wv;
    else if (mat == 3) W = Wi;
    else if (mat == 4) W = Wf;
    else if (mat == 5) W = Wo;

    const float4* Wrow = (const float4*)(W + (size_t)row * HD) + lane;
    const float4* sx4  = (const float4*)xs + lane;

    float a0 = 0.f, a1 = 0.f;
#pragma unroll
    for (int t = 0; t < 16; t += 2) {
        float4 w0 = Wrow[t * 64];
        float4 x0 = sx4[t * 64];
        float4 w1 = Wrow[(t + 1) * 64];
        float4 x1 = sx4[(t + 1) * 64];
        a0 += w0.x * x0.x + w0.y * x0.y + w0.z * x0.z + w0.w * x0.w;
        a1 += w1.x * x1.x + w1.y * x1.y + w1.z * x1.z + w1.w * x1.w;
    }
    float acc = a0 + a1;
#pragma unroll
    for (int off = 32; off > 0; off >>= 1)
        acc += __shfl_xor(acc, off, 64);

    if (lane == 0) ws_dots[(mat << 12) | row] = acc;
}

// ---------------------------------------------------------------------------
// Kernel 2: gate math + per-block partials of (n_t . q) AND (q . i_g*k).
// The latter two let k_ct compute h without putting the c_t store on the
// accumulator dependency chain:  c_t.q = dot(q*f_g, c_prev_row) + v_r * K.
// Also emits qfg[c] = q[c]*f_g[c] for k_ct's dot.
// ---------------------------------------------------------------------------
__global__ __launch_bounds__(256) void k_gates(
    const float* __restrict__ ws_dots,
    const float* __restrict__ bq, const float* __restrict__ bk,
    const float* __restrict__ bv, const float* __restrict__ bi,
    const float* __restrict__ bf, const float* __restrict__ bo,
    const float* __restrict__ n_prev, const float* __restrict__ m_prev,
    float* __restrict__ ws_q, float* __restrict__ ws_v,
    float* __restrict__ ws_o, float* __restrict__ ws_fg,
    float* __restrict__ ws_ik, float* __restrict__ ws_qfg,
    float* __restrict__ out_n, float* __restrict__ out_m,
    float* __restrict__ ws_nq, float* __restrict__ ws_Kp)
{
    const int tid = threadIdx.x;
    const int row = blockIdx.x * 256 + tid;

    float dq  = ws_dots[0 * HD + row];
    float dk  = ws_dots[1 * HD + row];
    float dv  = ws_dots[2 * HD + row];
    float di  = ws_dots[3 * HD + row];
    float df  = ws_dots[4 * HD + row];
    float d_o = ws_dots[5 * HD + row];

    float q  = dq + bq[row];
    float k  = (dk + bk[row]) * (1.0f / 64.0f);   // 1/sqrt(4096)
    float v  = dv + bv[row];
    float o  = 1.0f / (1.0f + expf(-(d_o + bo[row])));
    float it = di + bi[row];
    float ft = df + bf[row];
    float mp = m_prev[row];
    float mt = fmaxf(ft + mp, it);
    float ig = expf(it - mt);
    float fg = expf(ft + mp - mt);
    float ik = ig * k;
    float nt = fg * n_prev[row] + ik;

    ws_q[row]   = q;
    ws_v[row]   = v;
    ws_o[row]   = o;
    ws_fg[row]  = fg;
    ws_ik[row]  = ik;
    ws_qfg[row] = q * fg;
    out_n[row]  = nt;
    out_m[row]  = mt;

    float accN = nt * q;     // partial of n_t . q  (denominator)
    float accK = q * ik;     // partial of q . (i_g*k)  (h refactor scalar)
#pragma unroll
    for (int off = 32; off > 0; off >>= 1) {
        accN += __shfl_xor(accN, off, 64);
        accK += __shfl_xor(accK, off, 64);
    }
    __shared__ float redN[4], redK[4];
    if ((tid & 63) == 0) { redN[tid >> 6] = accN; redK[tid >> 6] = accK; }
    __syncthreads();
    if (tid == 0) {
        ws_nq[blockIdx.x] = redN[0] + redN[1] + redN[2] + redN[3];
        ws_Kp[blockIdx.x] = redK[0] + redK[1] + redK[2] + redK[3];
    }
}

// ---------------------------------------------------------------------------
// Kernel 3: c_t = f_g[c]*c_prev[r][c] + ik[c]*v[r]  (NT store, fire-and-forget)
// and h_t[r] = o[r] * (dot(qfg, c_prev[r,:]) + v[r]*K) / denom.
// The h-dot reads c_prev directly, so the out_c stores are OFF the dependency
// chain — loads stream at the read path, stores drain at the write path.
// 2 rows/block, 2048 blocks; den and K summed up-front by all threads.
// ---------------------------------------------------------------------------
__global__ __launch_bounds__(256) void k_ct(
    const float* __restrict__ c_prev,
    const float* __restrict__ ws_v, const float* __restrict__ ws_o,
    const float* __restrict__ ws_fg, const float* __restrict__ ws_ik,
    const float* __restrict__ ws_qfg,
    const float* __restrict__ ws_nq, const float* __restrict__ ws_Kp,
    float* __restrict__ out_h, float* __restrict__ out_c)
{
    const int row0 = blockIdx.x << 1;
    const int tid  = threadIdx.x;

    float den = 0.f, K = 0.f;
#pragma unroll
    for (int i = 0; i < 16; ++i) { den += ws_nq[i]; K += ws_Kp[i]; }
    den = fmaxf(fabsf(den), 1.0f);

    const float v0 = ws_v[row0];
    const float v1 = ws_v[row0 + 1];

    const v4f* cp0 = (const v4f*)(c_prev + (size_t)row0 * HD);
    const v4f* cp1 = cp0 + HD / 4;
    v4f*       ct0 = (v4f*)(out_c + (size_t)row0 * HD);
    v4f*       ct1 = ct0 + HD / 4;
    const v4f* fg4 = (const v4f*)ws_fg;
    const v4f* ik4 = (const v4f*)ws_ik;
    const v4f* qg4 = (const v4f*)ws_qfg;

    v4f c0[4], c1[4], f[4], k[4], qg[4];
#pragma unroll
    for (int t = 0; t < 4; ++t) {
        const int idx = t * 256 + tid;
        c0[t] = __builtin_nontemporal_load(&cp0[idx]);
        c1[t] = __builtin_nontemporal_load(&cp1[idx]);
        f[t]  = fg4[idx];
        k[t]  = ik4[idx];
        qg[t] = qg4[idx];
    }

    float acc0 = 0.f, acc1 = 0.f;
#pragma unroll
    for (int t = 0; t < 4; ++t) {
        const int idx = t * 256 + tid;
        // dot uses c_prev directly (not c_t): store is off the critical path
        acc0 += qg[t].x * c0[t].x + qg[t].y * c0[t].y
              + qg[t].z * c0[t].z + qg[t].w * c0[t].w;
        acc1 += qg[t].x * c1[t].x + qg[t].y * c1[t].y
              + qg[t].z * c1[t].z + qg[t].w * c1[t].w;
        v4f a = f[t] * c0[t] + k[t] * v0;
        v4f b = f[t] * c1[t] + k[t] * v1;
        __builtin_nontemporal_store(a, &ct0[idx]);
        __builtin_nontemporal_store(b, &ct1[idx]);
    }
#pragma unroll
    for (int off = 32; off > 0; off >>= 1) {
        acc0 += __shfl_xor(acc0, off, 64);
        acc1 += __shfl_xor(acc1, off, 64);
    }
    __shared__ float red[2][4];
    if ((tid & 63) == 0) {
        red[0][tid >> 6] = acc0;
        red[1][tid >> 6] = acc1;
    }
    __syncthreads();
    if (tid == 0) {
        float s0 = red[0][0] + red[0][1] + red[0][2] + red[0][3] + v0 * K;
        float s1 = red[1][0] + red[1][1] + red[1][2] + red[1][3] + v1 * K;
        out_h[row0]     = ws_o[row0]     * s0 / den;
        out_h[row0 + 1] = ws_o[row0 + 1] * s1 / den;
    }
}

// ---------------------------------------------------------------------------
extern "C" void kernel_launch(void* const* d_in, const int* in_sizes, int n_in,
                              void* d_out, int out_size, void* d_ws, size_t ws_size,
                              hipStream_t stream) {
    const float* x      = (const float*)d_in[0];
    /* d_in[1] = h_prev: unused by the reference */
    const float* c_prev = (const float*)d_in[2];
    const float* n_prev = (const float*)d_in[3];
    const float* m_prev = (const float*)d_in[4];
    const float* Wq = (const float*)d_in[5];  const float* bq = (const float*)d_in[6];
    const float* Wk = (const float*)d_in[7];  const float* bk = (const float*)d_in[8];
    const float* Wv = (const float*)d_in[9];  const float* bv = (const float*)d_in[10];
    const float* Wi = (const float*)d_in[11]; const float* bi = (const float*)d_in[12];
    const float* Wf = (const float*)d_in[13]; const float* bf = (const float*)d_in[14];
    const float* Wo = (const float*)d_in[15]; const float* bo = (const float*)d_in[16];

    // Output layout: h_t [H], c_t [H,H], n_t [H], m_t [H] — flat concat.
    float* out   = (float*)d_out;
    float* out_h = out;
    float* out_c = out + HD;
    float* out_n = out + HD + (size_t)HD * HD;
    float* out_m = out_n + HD;

    // Workspace layout (floats): dots[6*HD], q, v, o, fg, ik, qfg, nq[16], Kp[16]
    float* ws      = (float*)d_ws;
    float* ws_dots = ws;
    float* ws_q    = ws + 6 * HD;
    float* ws_v    = ws + 7 * HD;
    float* ws_o    = ws + 8 * HD;
    float* ws_fg   = ws + 9 * HD;
    float* ws_ik   = ws + 10 * HD;
    float* ws_qfg  = ws + 11 * HD;
    float* ws_nq   = ws + 12 * HD;        // 16 floats
    float* ws_Kp   = ws + 12 * HD + 16;   // 16 floats

    k_gemv<<<6 * 1024, 256, 0, stream>>>(x, Wq, Wk, Wv, Wi, Wf, Wo, ws_dots);
    k_gates<<<16, 256, 0, stream>>>(ws_dots, bq, bk, bv, bi, bf, bo,
                                    n_prev, m_prev,
                                    ws_q, ws_v, ws_o, ws_fg, ws_ik, ws_qfg,
                                    out_n, out_m, ws_nq, ws_Kp);
    k_ct<<<2048, 256, 0, stream>>>(c_prev, ws_v, ws_o, ws_fg, ws_ik, ws_qfg,
                                   ws_nq, ws_Kp, out_h, out_c);
}